// Round 5
// baseline (1050.370 us; speedup 1.0000x reference)
//
#include <hip/hip_runtime.h>
#include <stdint.h>
#include <stddef.h>

// AttentionGRUCell on MI355X (gfx950).  B=16384, EMB=1024, HID=1024, COMB=2048.
// ROUND-5: two-blocks-per-CU GEMM.  Round-4's 256x256 8-phase (1 block/CU,
// 8 lockstep waves) serializes LDS-read time with MFMA time (measured 28%
// MfmaUtil, 15k cyc/iter vs 4.1k MFMA floor).  New geometry: tile 128x256,
// BK=32, 8 waves (per-wave 64x64, acc 64 VGPR, frags 32), TRI-buffered LDS
// 3x24KB = 72KB -> 2 blocks/CU, launch_bounds(512,4) -> <=128 VGPR ->
// 16 waves/CU.  One barrier per K-tile; stage 2 tiles ahead; counted
// s_waitcnt vmcnt(3) (never 0 in main loop).  Cross-block TLP hides each
// block's read/barrier windows under the other block's MFMA.
//
// Memory choreography (cross-launch ordering makes input buffers reusable):
//   cvt_xh : x,h f32 -> x_bf (ws), h_bf (d_out t-region, dead until T)
//   cvt_a  : a f32   -> a_bf (x's input buffer, x f32 now dead)
//   transpose_all: 12 weights f32 [K,N] -> bf16 [N,K] in ws
//   R: rh = sigmoid(xWr+hUr+aCr)*h -> h-buffer[0:32M)      (h f32 dead)
//   Z: z  = sigmoid(xWz+hUz+aCz)   -> h-buffer[32M:64M)
//   S: s  = (1-z)h + z*tanh(xW+rhU+aC) -> d_out[0:64MB) f32, s_bf -> a-buffer
//   T: t  = relu(xVo+sUo+aCo)      -> d_out[64MB:128MB) f32 (over dead h_bf)

#define MODE_Z 0
#define MODE_R 1
#define MODE_S 2
#define MODE_T 3

typedef __attribute__((ext_vector_type(8))) __bf16 bf16x8;
typedef __attribute__((ext_vector_type(4))) float f32x4;
typedef __attribute__((ext_vector_type(8))) unsigned short us8;

__device__ __forceinline__ unsigned short f2bf(float f) {
  union { float f; unsigned u; } v; v.f = f;
  unsigned r = 0x7FFFu + ((v.u >> 16) & 1u);   // round-to-nearest-even
  return (unsigned short)((v.u + r) >> 16);
}
__device__ __forceinline__ float bf2f(unsigned short h) {
  union { unsigned u; float f; } v; v.u = ((unsigned)h) << 16;
  return v.f;
}

__device__ __forceinline__ void gload_lds16(const unsigned short* g, unsigned short* l) {
  __builtin_amdgcn_global_load_lds(
      (const __attribute__((address_space(1))) void*)g,
      (__attribute__((address_space(3))) void*)l, 16, 0, 0);
}

// Opaque LDS read (no alias-ordering vs global_load_lds LDS writes -> no
// compiler-inserted vmcnt(0) drains).  off = LDS byte offset, IMM = imm add.
template <int IMM>
__device__ __forceinline__ bf16x8 dsr128i(unsigned off) {
  bf16x8 r;
  asm volatile("ds_read_b128 %0, %1 offset:%2" : "=v"(r) : "v"(off), "i"(IMM));
  return r;
}

// ---- f32 -> bf16 converters (8 elems/thread, fully coalesced) ----
__global__ void cvt_xh(const float* __restrict__ x, const float* __restrict__ h,
                       unsigned short* __restrict__ xb, unsigned short* __restrict__ hb) {
  const size_t NX = 16777216;  // 16384*1024
  size_t i = ((size_t)blockIdx.x * 256 + threadIdx.x) * 8;
  const float* s; unsigned short* d; size_t off;
  if (i < NX) { s = x; d = xb; off = i; } else { s = h; d = hb; off = i - NX; }
  f32x4 v0 = *(const f32x4*)(s + off);
  f32x4 v1 = *(const f32x4*)(s + off + 4);
  us8 p = { f2bf(v0.x), f2bf(v0.y), f2bf(v0.z), f2bf(v0.w),
            f2bf(v1.x), f2bf(v1.y), f2bf(v1.z), f2bf(v1.w) };
  *(us8*)(d + off) = p;
}

__global__ void cvt_a(const float* __restrict__ a, unsigned short* __restrict__ ab) {
  size_t i = ((size_t)blockIdx.x * 256 + threadIdx.x) * 8;
  f32x4 v0 = *(const f32x4*)(a + i);
  f32x4 v1 = *(const f32x4*)(a + i + 4);
  us8 p = { f2bf(v0.x), f2bf(v0.y), f2bf(v0.z), f2bf(v0.w),
            f2bf(v1.x), f2bf(v1.y), f2bf(v1.z), f2bf(v1.w) };
  *(us8*)(ab + i) = p;
}

// ---- batched weight transpose: f32 [K,1024] -> bf16 [1024,K] ----
struct TArgs {
  const float* src[12];
  unsigned short* dst[12];
};

__global__ void transpose_all(TArgs ta) {
  __shared__ float tile[32][33];
  int t = blockIdx.x;
  int w, K, local;
  if (t < 8192) { w = t >> 10; K = 1024; local = t & 1023; }
  else { int t2 = t - 8192; w = 8 + (t2 >> 11); K = 2048; local = t2 & 2047; }
  int kb = (K == 1024) ? ((local & 31) << 5) : ((local & 63) << 5);
  int nb = (K == 1024) ? ((local >> 5) << 5) : ((local >> 6) << 5);
  const float* src = ta.src[w];
  unsigned short* dst = ta.dst[w];
  int tx = threadIdx.x, ty = threadIdx.y;   // block 32x8
  #pragma unroll
  for (int i = 0; i < 32; i += 8)
    tile[ty + i][tx] = src[(size_t)(kb + ty + i) * 1024 + nb + tx];
  __syncthreads();
  #pragma unroll
  for (int i = 0; i < 32; i += 8)
    dst[(size_t)(nb + ty + i) * K + kb + tx] = f2bf(tile[tx][ty + i]);
}

#define BARRIER()     __builtin_amdgcn_s_barrier()
#define WAIT_VM(N)    asm volatile("s_waitcnt vmcnt(" #N ")")
#define SCHED_FENCE() __builtin_amdgcn_sched_barrier(0)
// rule #18: explicit lgkmcnt for asm ds_reads + sched fence so MFMA can't hoist
#define WAIT_LGKM0()  do { asm volatile("s_waitcnt lgkmcnt(0)"); \
                           __builtin_amdgcn_sched_barrier(0); } while (0)
#define PRIO1()       __builtin_amdgcn_s_setprio(1)
#define PRIO0()       __builtin_amdgcn_s_setprio(0)

// ---- fused GEMM: 128x256 tile, BK=32, 8 waves 2Mx4N (64x64 each) ----
// LDS: 3 buffers x 24 KB: A (128 rows x 32k bf16 = 8 KB) then B (256 cols
// x 32k = 16 KB).  Row byte layout: row r at r*64, 4 slots of 16B; slot s
// holds kgroup s ^ ((r>>1)&3) (source pre-swizzled) -> ds_read_b128 at
// slot = quad ^ ((lm>>1)&3) is conflict-free (8 distinct bank-quads per 8
// rows, 2-way alias = free).  128 K-tiles (K=4096, 3 segments).
template <int MODE>
__global__ __launch_bounds__(512, 4)
void gemm_fused(const unsigned short* __restrict__ A0,   // K=1024
                const unsigned short* __restrict__ A1,   // K=1024
                const unsigned short* __restrict__ A2,   // K=2048
                const unsigned short* __restrict__ B0T,
                const unsigned short* __restrict__ B1T,
                const unsigned short* __restrict__ B2T,
                const float* __restrict__ b0,
                const float* __restrict__ b1,
                const float* __restrict__ b2,
                const unsigned short* __restrict__ hb,   // h bf16 (R,S)
                const unsigned short* __restrict__ zb,   // z bf16 (S)
                float* __restrict__ outf,
                unsigned short* __restrict__ outb) {
  __shared__ unsigned short lds_s[36864];   // 72 KiB = 3 x 24 KiB

  const int tid = threadIdx.x;
  const int bid = blockIdx.x;
  // XCD swizzle: 512 blocks, bid&7 = XCD; 4 consecutive swz share an A-slab
  // (same mBlk) and land on the same XCD's L2.
  const int swz = (bid & 7) * 64 + (bid >> 3);
  const int mBlk = swz >> 2;                 // 0..127
  const int nBlk = swz & 3;                  // 0..3
  const int rowBase = mBlk << 7;             // *128
  const int colBase = nBlk << 8;             // *256

  const int l = tid & 63;
  const int w = tid >> 6;                    // wave 0..7
  const int wm = w >> 2;                     // 0..1
  const int wn = w & 3;                      // 0..3
  const int lm = l & 15;
  const int quad = l >> 4;

  // ds-read constant bases (byte offsets within one 24 KB buffer)
  const unsigned slotA = (unsigned)(quad ^ ((lm >> 1) & 3));
  const unsigned base_a = (unsigned)((wm * 64 + lm) * 64) + (slotA << 4);
  const unsigned base_b = 8192u + (unsigned)((wn * 64 + lm) * 64) + (slotA << 4);

  // stage constant per-thread source offsets (bytes within segment buffers)
  const int rA = tid >> 2;                              // 0..127
  const unsigned kg16 = (unsigned)(((tid & 3) ^ ((rA >> 1) & 3)) << 4);
  const unsigned voA1 = (unsigned)(rowBase + rA) * 2048u + kg16;  // K=1024
  const unsigned voA2 = (unsigned)(rowBase + rA) * 4096u + kg16;  // K=2048
  const unsigned voB0_1 = (unsigned)(colBase + rA) * 2048u + kg16;
  const unsigned voB1_1 = (unsigned)(colBase + 128 + rA) * 2048u + kg16;
  const unsigned voB0_2 = (unsigned)(colBase + rA) * 4096u + kg16;
  const unsigned voB1_2 = (unsigned)(colBase + 128 + rA) * 4096u + kg16;

  f32x4 acc[4][4];                           // [fr][fc]
  #pragma unroll
  for (int fr = 0; fr < 4; ++fr)
    #pragma unroll
    for (int fc = 0; fc < 4; ++fc)
      acc[fr][fc] = (f32x4){0.f, 0.f, 0.f, 0.f};

  // stage one full 24 KB K-tile kt into buffer at byte soff (3 gloads/thread)
  auto STAGE = [&](int kt, int soff) {
    const unsigned short *bA, *bB;
    int tl; unsigned voA, voB0, voB1;
    if (kt < 32)      { bA = A0; bB = B0T; tl = kt;
                        voA = voA1; voB0 = voB0_1; voB1 = voB1_1; }
    else if (kt < 64) { bA = A1; bB = B1T; tl = kt - 32;
                        voA = voA1; voB0 = voB0_1; voB1 = voB1_1; }
    else              { bA = A2; bB = B2T; tl = kt - 64;
                        voA = voA2; voB0 = voB0_2; voB1 = voB1_2; }
    const unsigned tb = (unsigned)(tl << 6);           // tloc * 64 bytes
    unsigned short* ldsb = lds_s + (soff >> 1);
    gload_lds16((const unsigned short*)((const char*)bA + voA + tb),
                ldsb + tid * 8);
    gload_lds16((const unsigned short*)((const char*)bB + voB0 + tb),
                ldsb + 4096 + tid * 8);
    gload_lds16((const unsigned short*)((const char*)bB + voB1 + tb),
                ldsb + 8192 + tid * 8);
  };

  bf16x8 aF[4], bF[4];
  auto READS = [&](int bufoff) {
    const unsigned vA = (unsigned)bufoff + base_a;
    const unsigned vB = (unsigned)bufoff + base_b;
    aF[0] = dsr128i<0>(vA);    aF[1] = dsr128i<1024>(vA);
    aF[2] = dsr128i<2048>(vA); aF[3] = dsr128i<3072>(vA);
    bF[0] = dsr128i<0>(vB);    bF[1] = dsr128i<1024>(vB);
    bF[2] = dsr128i<2048>(vB); bF[3] = dsr128i<3072>(vB);
  };
  auto MFMA16 = [&]() {
    #pragma unroll
    for (int fr = 0; fr < 4; ++fr)
      #pragma unroll
      for (int fc = 0; fc < 4; ++fc)
        acc[fr][fc] = __builtin_amdgcn_mfma_f32_16x16x32_bf16(
            aF[fr], bF[fc], acc[fr][fc], 0, 0, 0);
  };

  // ---- prologue: stage tiles 0,1; wait tile 0 (3 newest = tile 1) ----
  STAGE(0, 0);
  STAGE(1, 24576);
  WAIT_VM(3);
  BARRIER(); SCHED_FENCE();

  // ---- main loop: 1 phase per K-tile, tiles 0..125 stage t+2 ----
  int bufoff = 0;            // buffer holding tile t
  int stageoff = 49152;      // buffer for tile t+2
  #pragma unroll 1
  for (int t = 0; t < 126; ++t) {
    READS(bufoff);
    STAGE(t + 2, stageoff);
    WAIT_LGKM0();
    PRIO1(); MFMA16(); PRIO0();
    WAIT_VM(3);              // tile t+1 landed (3 newest = tile t+2)
    BARRIER(); SCHED_FENCE();
    bufoff = stageoff;       // t+1's buffer is (bufoff+24576)%73728 == old stage-1...
    // cycle: next tile's buffer / next stage buffer
    int nb = (bufoff == 0) ? 24576 : (bufoff == 24576 ? 49152 : 0);
    // bufoff currently holds old stageoff (tile t+2's buf); tile t+1's buf:
    bufoff = nb == 24576 ? 49152 : (nb == 49152 ? 0 : 24576);
    // recompute cleanly to avoid confusion:
    bufoff = ((t + 1) % 3) * 24576;
    stageoff = ((t + 3) % 3) * 24576;
  }
  // ---- peeled tile 126: no stage; drain last staging (tile 127) ----
  READS(bufoff);
  WAIT_LGKM0();
  PRIO1(); MFMA16(); PRIO0();
  WAIT_VM(0);
  BARRIER(); SCHED_FENCE();
  bufoff = (127 % 3) * 24576;
  // ---- peeled tile 127 ----
  READS(bufoff);
  WAIT_LGKM0();
  PRIO1(); MFMA16(); PRIO0();

  // Compiler-only fence: keep epilogue global loads from hoisting above the
  // counted vmcnt waits.
  asm volatile("" ::: "memory");

  // ---- fused epilogue. C/D layout: col = lane&15, row = quad*4 + reg ----
  #pragma unroll
  for (int fc = 0; fc < 4; ++fc) {
    const int col = colBase + wn * 64 + fc * 16 + lm;
    const float bias = b0[col] + b1[col] + b2[col];
    #pragma unroll
    for (int fr = 0; fr < 4; ++fr) {
      #pragma unroll
      for (int r = 0; r < 4; ++r) {
        const int row = rowBase + wm * 64 + fr * 16 + quad * 4 + r;
        const size_t idx = (size_t)row * 1024 + col;
        float v = acc[fr][fc][r] + bias;
        if constexpr (MODE == MODE_Z) {
          outb[idx] = f2bf(1.f / (1.f + __expf(-v)));
        } else if constexpr (MODE == MODE_R) {
          float rv = 1.f / (1.f + __expf(-v));
          outb[idx] = f2bf(rv * bf2f(hb[idx]));
        } else if constexpr (MODE == MODE_S) {
          float avv = fabsf(v);
          float e = __expf(-2.f * avv);
          float st = (1.f - e) / (1.f + e);      // |tanh|
          st = v < 0.f ? -st : st;
          float zv = bf2f(zb[idx]);
          float hv = bf2f(hb[idx]);
          float s = (1.f - zv) * hv + zv * st;
          outf[idx] = s;
          outb[idx] = f2bf(s);
        } else {  // MODE_T
          outf[idx] = v > 0.f ? v : 0.f;
        }
      }
    }
  }
}

extern "C" void kernel_launch(void* const* d_in, const int* in_sizes, int n_in,
                              void* d_out, int out_size, void* d_ws, size_t ws_size,
                              hipStream_t stream) {
  (void)in_sizes; (void)n_in; (void)out_size; (void)ws_size;
  const float* x  = (const float*)d_in[0];   // [16384,1024]
  const float* h  = (const float*)d_in[1];   // [16384,1024]
  const float* a  = (const float*)d_in[2];   // [16384,2048]
  const float* W   = (const float*)d_in[3];  const float* bw  = (const float*)d_in[4];
  const float* Wz  = (const float*)d_in[5];  const float* bwz = (const float*)d_in[6];
  const float* Wr  = (const float*)d_in[7];  const float* bwr = (const float*)d_in[8];
  const float* U   = (const float*)d_in[9];  const float* bu  = (const float*)d_in[10];
  const float* Uz  = (const float*)d_in[11]; const float* buz = (const float*)d_in[12];
  const float* Ur  = (const float*)d_in[13]; const float* bur = (const float*)d_in[14];
  const float* C   = (const float*)d_in[15]; const float* bc  = (const float*)d_in[16];
  const float* Cz  = (const float*)d_in[17]; const float* bcz = (const float*)d_in[18];
  const float* Cr  = (const float*)d_in[19]; const float* bcr = (const float*)d_in[20];
  const float* Uo  = (const float*)d_in[21]; const float* buo = (const float*)d_in[22];
  const float* Vo  = (const float*)d_in[23]; const float* bvo = (const float*)d_in[24];
  const float* Co  = (const float*)d_in[25]; const float* bco = (const float*)d_in[26];

  const size_t M1 = 1024u * 1024u;           // 1M elements
  unsigned short* wsb = (unsigned short*)d_ws;
  // ws: 12 transposed bf16 weights (32 MB) + x_bf (32 MB) = 64 MB used.
  unsigned short* WzT = wsb + 0 * M1;
  unsigned short* UzT = wsb + 1 * M1;
  unsigned short* WrT = wsb + 2 * M1;
  unsigned short* UrT = wsb + 3 * M1;
  unsigned short* WT  = wsb + 4 * M1;
  unsigned short* UT  = wsb + 5 * M1;
  unsigned short* VoT = wsb + 6 * M1;
  unsigned short* UoT = wsb + 7 * M1;
  unsigned short* CzT = wsb + 8 * M1;        // 2M each from here
  unsigned short* CrT = wsb + 10 * M1;
  unsigned short* CT  = wsb + 12 * M1;
  unsigned short* CoT = wsb + 14 * M1;
  unsigned short* x_bf = wsb + 16 * M1;      // 16M elems

  // Scratch carved out of dead buffers (cross-launch ordering, see header):
  unsigned short* h_bf = (unsigned short*)((float*)d_out + 16 * M1); // d_out t-region
  unsigned short* a_bf = (unsigned short*)d_in[0];                   // x f32 dead after cvt_xh
  unsigned short* rh   = (unsigned short*)d_in[1];                   // h f32 dead after cvt_xh
  unsigned short* z_bf = (unsigned short*)d_in[1] + 16 * M1;
  unsigned short* s_bf = (unsigned short*)d_in[2];                   // a f32 dead after cvt_a

  float* s_out = (float*)d_out;
  float* t_out = (float*)d_out + 16 * M1;

  // 1) convert x,h (must precede a_bf overwriting x's buffer)
  cvt_xh<<<16384, 256, 0, stream>>>(x, h, x_bf, h_bf);
  // 2) convert a into x's (now dead) buffer
  cvt_a<<<16384, 256, 0, stream>>>(a, a_bf);
  // 3) all 12 weight transposes in one launch
  TArgs ta;
  const float* wsrc[12] = {Wz, Uz, Wr, Ur, W, U, Vo, Uo, Cz, Cr, C, Co};
  unsigned short* wdst[12] = {WzT, UzT, WrT, UrT, WT, UT, VoT, UoT, CzT, CrT, CT, CoT};
  for (int i = 0; i < 12; ++i) { ta.src[i] = wsrc[i]; ta.dst[i] = wdst[i]; }
  transpose_all<<<16384, dim3(32, 8), 0, stream>>>(ta);

  dim3 g(512), b(512);
  gemm_fused<MODE_R><<<g, b, 0, stream>>>(x_bf, h_bf, a_bf, WrT, UrT, CrT,
                                          bwr, bur, bcr, h_bf, nullptr, nullptr, rh);
  gemm_fused<MODE_Z><<<g, b, 0, stream>>>(x_bf, h_bf, a_bf, WzT, UzT, CzT,
                                          bwz, buz, bcz, nullptr, nullptr, nullptr, z_bf);
  gemm_fused<MODE_S><<<g, b, 0, stream>>>(x_bf, rh, a_bf, WT, UT, CT,
                                          bw, bu, bc, h_bf, z_bf, s_out, s_bf);
  gemm_fused<MODE_T><<<g, b, 0, stream>>>(x_bf, s_bf, a_bf, VoT, UoT, CoT,
                                          bvo, buo, bco, nullptr, nullptr, t_out, nullptr);
}